// Round 5
// baseline (50000.595 us; speedup 1.0000x reference)
//
#include <hip/hip_runtime.h>
#include <hip/hip_fp16.h>
#include <math.h>

// ---------------------------------------------------------------------------
// V projection precompute (fp32 SGEMM, fp16 out): out[b][h][m][d], row-major [m][d]
// ---------------------------------------------------------------------------
__global__ __launch_bounds__(256) void kv_proj(
    const float* __restrict__ mem, const float* __restrict__ W,
    const float* __restrict__ bias, __half* __restrict__ outp) {
  __shared__ float As[32][68];
  __shared__ float Bs[32][68];
  int gid = blockIdx.x;
  int jt = gid & 7, mt = (gid >> 3) & 7, b = gid >> 6;
  int t = threadIdx.x;
  int lm = t >> 2;
  int kq = (t & 3) * 8;
  int tx = t & 15, ty = t >> 4;
  float acc[4][4];
  #pragma unroll
  for (int r = 0; r < 4; ++r)
    #pragma unroll
    for (int c = 0; c < 4; ++c) acc[r][c] = 0.f;
  const float* Arow = mem + (size_t)(mt * 64 + lm) * 65536 + (size_t)b * 512 + kq;
  const float* Brow = W + (size_t)(jt * 64 + lm) * 512 + kq;
  for (int k0 = 0; k0 < 512; k0 += 32) {
    float4 a0 = *(const float4*)(Arow + k0);
    float4 a1 = *(const float4*)(Arow + k0 + 4);
    float4 b0 = *(const float4*)(Brow + k0);
    float4 b1 = *(const float4*)(Brow + k0 + 4);
    As[kq + 0][lm] = a0.x; As[kq + 1][lm] = a0.y; As[kq + 2][lm] = a0.z; As[kq + 3][lm] = a0.w;
    As[kq + 4][lm] = a1.x; As[kq + 5][lm] = a1.y; As[kq + 6][lm] = a1.z; As[kq + 7][lm] = a1.w;
    Bs[kq + 0][lm] = b0.x; Bs[kq + 1][lm] = b0.y; Bs[kq + 2][lm] = b0.z; Bs[kq + 3][lm] = b0.w;
    Bs[kq + 4][lm] = b1.x; Bs[kq + 5][lm] = b1.y; Bs[kq + 6][lm] = b1.z; Bs[kq + 7][lm] = b1.w;
    __syncthreads();
    #pragma unroll
    for (int k = 0; k < 32; ++k) {
      float4 av = *(const float4*)&As[k][ty * 4];
      float4 bv = *(const float4*)&Bs[k][tx * 4];
      float ar[4] = {av.x, av.y, av.z, av.w};
      float br[4] = {bv.x, bv.y, bv.z, bv.w};
      #pragma unroll
      for (int r = 0; r < 4; ++r)
        #pragma unroll
        for (int c = 0; c < 4; ++c) acc[r][c] = fmaf(ar[r], br[c], acc[r][c]);
    }
    __syncthreads();
  }
  float4 bb = *(const float4*)(bias + jt * 64 + tx * 4);
  #pragma unroll
  for (int r = 0; r < 4; ++r) {
    int m = mt * 64 + ty * 4 + r;
    __half2 p0 = __floats2half2_rn(acc[r][0] + bb.x, acc[r][1] + bb.y);
    __half2 p1 = __floats2half2_rn(acc[r][2] + bb.z, acc[r][3] + bb.w);
    union { uint2 u; __half2 h[2]; } W2;
    W2.h[0] = p0; W2.h[1] = p1;
    *(uint2*)(outp + (((size_t)b * 8 + jt) * 512 + m) * 64 + tx * 4) = W2.u;
  }
}

// ---------------------------------------------------------------------------
// K projection, TRANSPOSED fp16 output: out[b][h][d][m]  (d = head-local 0..63)
// ---------------------------------------------------------------------------
__global__ __launch_bounds__(256) void kv_projT(
    const float* __restrict__ mem, const float* __restrict__ W,
    const float* __restrict__ bias, __half* __restrict__ outp) {
  __shared__ float As[32][68];
  __shared__ float Bs[32][68];
  int gid = blockIdx.x;
  int jt = gid & 7, mt = (gid >> 3) & 7, b = gid >> 6;
  int t = threadIdx.x;
  int lm = t >> 2;
  int kq = (t & 3) * 8;
  int tx = t & 15, ty = t >> 4;
  float acc[4][4];
  #pragma unroll
  for (int r = 0; r < 4; ++r)
    #pragma unroll
    for (int c = 0; c < 4; ++c) acc[r][c] = 0.f;
  const float* Arow = mem + (size_t)(mt * 64 + lm) * 65536 + (size_t)b * 512 + kq;
  const float* Brow = W + (size_t)(jt * 64 + lm) * 512 + kq;
  for (int k0 = 0; k0 < 512; k0 += 32) {
    float4 a0 = *(const float4*)(Arow + k0);
    float4 a1 = *(const float4*)(Arow + k0 + 4);
    float4 b0 = *(const float4*)(Brow + k0);
    float4 b1 = *(const float4*)(Brow + k0 + 4);
    As[kq + 0][lm] = a0.x; As[kq + 1][lm] = a0.y; As[kq + 2][lm] = a0.z; As[kq + 3][lm] = a0.w;
    As[kq + 4][lm] = a1.x; As[kq + 5][lm] = a1.y; As[kq + 6][lm] = a1.z; As[kq + 7][lm] = a1.w;
    Bs[kq + 0][lm] = b0.x; Bs[kq + 1][lm] = b0.y; Bs[kq + 2][lm] = b0.z; Bs[kq + 3][lm] = b0.w;
    Bs[kq + 4][lm] = b1.x; Bs[kq + 5][lm] = b1.y; Bs[kq + 6][lm] = b1.z; Bs[kq + 7][lm] = b1.w;
    __syncthreads();
    #pragma unroll
    for (int k = 0; k < 32; ++k) {
      float4 av = *(const float4*)&As[k][ty * 4];
      float4 bv = *(const float4*)&Bs[k][tx * 4];
      float ar[4] = {av.x, av.y, av.z, av.w};
      float br[4] = {bv.x, bv.y, bv.z, bv.w};
      #pragma unroll
      for (int r = 0; r < 4; ++r)
        #pragma unroll
        for (int c = 0; c < 4; ++c) acc[r][c] = fmaf(ar[r], br[c], acc[r][c]);
    }
    __syncthreads();
  }
  float4 bb = *(const float4*)(bias + jt * 64 + tx * 4);
  float bc[4] = {bb.x, bb.y, bb.z, bb.w};
  #pragma unroll
  for (int r = 0; r < 4; ++r) {
    int m = mt * 64 + ty * 4 + r;
    #pragma unroll
    for (int c = 0; c < 4; ++c) {
      int d = tx * 4 + c;  // head-local dim
      outp[((size_t)(b * 8 + jt) * 64 + d) * 512 + m] = __float2half_rn(acc[r][c] + bc[c]);
    }
  }
}

// ---------------------------------------------------------------------------
// E2 = emb @ Wq[:, :512]^T + bq   -> [1000][512] fp32 (embedding half of q-proj)
// ---------------------------------------------------------------------------
__global__ __launch_bounds__(256) void e2_kernel(
    const float* __restrict__ emb, const float* __restrict__ Wq,
    const float* __restrict__ bq, float* __restrict__ E2) {
  __shared__ float As[32][68];
  __shared__ float Bs[32][68];
  int gid = blockIdx.x;
  int jt = gid & 7, mt = gid >> 3;
  int t = threadIdx.x;
  int lm = t >> 2;
  int kq = (t & 3) * 8;
  int tx = t & 15, ty = t >> 4;
  float acc[4][4];
  #pragma unroll
  for (int r = 0; r < 4; ++r)
    #pragma unroll
    for (int c = 0; c < 4; ++c) acc[r][c] = 0.f;
  int v = mt * 64 + lm;
  bool aok = v < 1000;
  const float* Arow = emb + (size_t)v * 512 + kq;
  const float* Brow = Wq + (size_t)(jt * 64 + lm) * 1024 + kq;  // emb-half cols [0,512)
  for (int k0 = 0; k0 < 512; k0 += 32) {
    float4 a0, a1;
    if (aok) {
      a0 = *(const float4*)(Arow + k0);
      a1 = *(const float4*)(Arow + k0 + 4);
    } else {
      a0 = make_float4(0.f, 0.f, 0.f, 0.f);
      a1 = make_float4(0.f, 0.f, 0.f, 0.f);
    }
    float4 b0 = *(const float4*)(Brow + k0);
    float4 b1 = *(const float4*)(Brow + k0 + 4);
    As[kq + 0][lm] = a0.x; As[kq + 1][lm] = a0.y; As[kq + 2][lm] = a0.z; As[kq + 3][lm] = a0.w;
    As[kq + 4][lm] = a1.x; As[kq + 5][lm] = a1.y; As[kq + 6][lm] = a1.z; As[kq + 7][lm] = a1.w;
    Bs[kq + 0][lm] = b0.x; Bs[kq + 1][lm] = b0.y; Bs[kq + 2][lm] = b0.z; Bs[kq + 3][lm] = b0.w;
    Bs[kq + 4][lm] = b1.x; Bs[kq + 5][lm] = b1.y; Bs[kq + 6][lm] = b1.z; Bs[kq + 7][lm] = b1.w;
    __syncthreads();
    #pragma unroll
    for (int k = 0; k < 32; ++k) {
      float4 av = *(const float4*)&As[k][ty * 4];
      float4 bv = *(const float4*)&Bs[k][tx * 4];
      float ar[4] = {av.x, av.y, av.z, av.w};
      float br[4] = {bv.x, bv.y, bv.z, bv.w};
      #pragma unroll
      for (int r = 0; r < 4; ++r)
        #pragma unroll
        for (int c = 0; c < 4; ++c) acc[r][c] = fmaf(ar[r], br[c], acc[r][c]);
    }
    __syncthreads();
  }
  float4 bb = *(const float4*)(bq + jt * 64 + tx * 4);
  float bc[4] = {bb.x, bb.y, bb.z, bb.w};
  #pragma unroll
  for (int r = 0; r < 4; ++r) {
    int vv = mt * 64 + ty * 4 + r;
    if (vv < 1000) {
      #pragma unroll
      for (int c = 0; c < 4; ++c)
        E2[(size_t)vv * 512 + jt * 64 + tx * 4 + c] = acc[r][c] + bc[c];
    }
  }
}

// ---------------------------------------------------------------------------
__global__ __launch_bounds__(256) void init_kernel(float* __restrict__ h0) {
  int t = threadIdx.x + blockIdx.x * blockDim.x;
  for (int i = t; i < 128 * 512; i += blockDim.x * gridDim.x) h0[i] = 0.f;
}

// ---------------------------------------------------------------------------
// FULLY-FUSED per-step kernel. One block per batch (grid 128, 512 threads).
// Chain (all block-local, zero cross-block traffic):
//   step>0:   logits(step-1) -> out_o, argmax -> tok, qh = h.Wq_h (regs)
//   step<160: q = E2[tok]+qh; scores+softmax (wave per head); scores-mean;
//             ctx = att.V  (stays in LDS);  GRU -> h_new, out_h
//   step==160: epilogue, logits only.
// ---------------------------------------------------------------------------
__global__ __launch_bounds__(512) void step_kernel(
    const __half* __restrict__ kpT, const __half* __restrict__ vp,
    const float* __restrict__ E2, const float* __restrict__ Wfc,
    const float* __restrict__ bfc, const float* __restrict__ Wq,
    const float* __restrict__ W_ih, const float* __restrict__ W_hh,
    const float* __restrict__ b_ih, const float* __restrict__ b_hh,
    const float* __restrict__ h_prev, float* __restrict__ h_new,
    const int* __restrict__ lens, float* __restrict__ out_o,
    float* __restrict__ out_h, float* __restrict__ out_s, int step) {
  int b = blockIdx.x;
  int t = threadIdx.x;
  __shared__ __align__(16) float hs[512];
  __shared__ __align__(16) float qs[512];
  __shared__ __align__(16) float att[8][512];
  __shared__ __align__(16) float ctxs[512];
  __shared__ float redv[8];
  __shared__ int redi[8];
  __shared__ int tok_s;

  if (step > 0) {
    hs[t] = h_prev[(size_t)b * 512 + t];
    __syncthreads();
    // ---- logits(step-1): thread owns v = t and v2 = t+512 (register-blocked,
    //      one LDS h-read feeds both rows) ----
    int run = (step - 1) < lens[b];
    bool v1ok = (t + 512) < 1000;
    float a0 = bfc[t];
    float a1 = v1ok ? bfc[t + 512] : 0.f;
    const float* w0 = Wfc + (size_t)t * 512;
    const float* w1 = Wfc + (size_t)(v1ok ? t + 512 : t) * 512;
    #pragma unroll 4
    for (int k = 0; k < 512; k += 4) {
      float4 h4 = *(const float4*)&hs[k];
      float4 wa = *(const float4*)(w0 + k);
      float4 wb = *(const float4*)(w1 + k);
      a0 = fmaf(h4.x, wa.x, a0); a0 = fmaf(h4.y, wa.y, a0);
      a0 = fmaf(h4.z, wa.z, a0); a0 = fmaf(h4.w, wa.w, a0);
      a1 = fmaf(h4.x, wb.x, a1); a1 = fmaf(h4.y, wb.y, a1);
      a1 = fmaf(h4.z, wb.z, a1); a1 = fmaf(h4.w, wb.w, a1);
    }
    out_o[(size_t)(step - 1) * 128000 + (size_t)b * 1000 + t] = run ? a0 : 0.f;
    if (v1ok)
      out_o[(size_t)(step - 1) * 128000 + (size_t)b * 1000 + t + 512] = run ? a1 : 0.f;
    if (step >= 160) return;  // epilogue: logits only

    float bestv = a0;
    int besti = t;
    if (v1ok && a1 > a0) { bestv = a1; besti = t + 512; }
    #pragma unroll
    for (int o = 32; o > 0; o >>= 1) {
      float ov = __shfl_xor(bestv, o);
      int oi = __shfl_xor(besti, o);
      if (ov > bestv || (ov == bestv && oi < besti)) { bestv = ov; besti = oi; }
    }
    if ((t & 63) == 0) { redv[t >> 6] = bestv; redi[t >> 6] = besti; }
    // ---- qh row t (h-half of Wq) while argmax settles ----
    float qhv = 0.f;
    {
      const float* wrow = Wq + (size_t)t * 1024 + 512;
      #pragma unroll 4
      for (int k = 0; k < 512; k += 4) {
        float4 h4 = *(const float4*)&hs[k];
        float4 w = *(const float4*)(wrow + k);
        qhv = fmaf(h4.x, w.x, qhv); qhv = fmaf(h4.y, w.y, qhv);
        qhv = fmaf(h4.z, w.z, qhv); qhv = fmaf(h4.w, w.w, qhv);
      }
    }
    __syncthreads();
    if (t == 0) {
      float bv = redv[0];
      int bi = redi[0];
      #pragma unroll
      for (int i = 1; i < 8; ++i)
        if (redv[i] > bv || (redv[i] == bv && redi[i] < bi)) { bv = redv[i]; bi = redi[i]; }
      tok_s = bi;
    }
    __syncthreads();
    qs[t] = qhv + E2[(size_t)tok_s * 512 + t];
    __syncthreads();
  } else {
    hs[t] = 0.f;               // h_prev = 0 at t=0
    qs[t] = E2[t];             // tok = 0 (argmax of zero logits), qh = 0
    __syncthreads();
  }

  // ---- scores: wave per head (hd = t>>6); lane owns m = 2*(lane+64i)+{0,1} ----
  int hd = t >> 6, lane = t & 63;
  const __half* Kb = kpT + (size_t)(b * 8 + hd) * 32768;  // [64][512]
  float s0[4], s1[4];
  #pragma unroll
  for (int i = 0; i < 4; ++i) { s0[i] = 0.f; s1[i] = 0.f; }
  for (int d = 0; d < 64; ++d) {
    float qd = qs[hd * 64 + d];
    const __half* kr = Kb + (size_t)d * 512;
    #pragma unroll
    for (int i = 0; i < 4; ++i) {
      __half2 kk = *(const __half2*)(kr + 2 * (lane + 64 * i));
      float2 kf = __half22float2(kk);
      s0[i] = fmaf(qd, kf.x, s0[i]);
      s1[i] = fmaf(qd, kf.y, s1[i]);
    }
  }
  float mx = -1e30f;
  #pragma unroll
  for (int i = 0; i < 4; ++i) {
    s0[i] *= 0.125f;  // 1/sqrt(64)
    s1[i] *= 0.125f;
    mx = fmaxf(mx, fmaxf(s0[i], s1[i]));
  }
  #pragma unroll
  for (int o = 32; o > 0; o >>= 1) mx = fmaxf(mx, __shfl_xor(mx, o));
  float e0[4], e1[4], sm = 0.f;
  #pragma unroll
  for (int i = 0; i < 4; ++i) {
    e0[i] = expf(s0[i] - mx);
    e1[i] = expf(s1[i] - mx);
    sm += e0[i] + e1[i];
  }
  #pragma unroll
  for (int o = 32; o > 0; o >>= 1) sm += __shfl_xor(sm, o);
  float inv = 1.f / sm;
  #pragma unroll
  for (int i = 0; i < 4; ++i)
    *(float2*)&att[hd][2 * (lane + 64 * i)] = make_float2(e0[i] * inv, e1[i] * inv);
  __syncthreads();

  // ---- scores output: mean over heads (m = t) ----
  {
    float sum2 = 0.f;
    #pragma unroll
    for (int h2 = 0; h2 < 8; ++h2) sum2 += att[h2][t];
    out_s[(size_t)step * 65536 + (size_t)b * 512 + t] =
        (step < lens[b]) ? sum2 * 0.125f : 0.f;
  }

  // ---- ctx: wave hd; lane = (g = lane>>4, dsl = (lane&15)*4); m += 4 stride;
  //      uint2 = 4 halves per load (8B/lane), xor-shuffle reduce over 4 groups ----
  const __half* Vb = vp + (size_t)(b * 8 + hd) * 32768;  // [512][64]
  {
    int dsl = (lane & 15) * 4, g4 = lane >> 4;
    float c0 = 0.f, c1 = 0.f, c2 = 0.f, c3 = 0.f;
    #pragma unroll 8
    for (int m = g4; m < 512; m += 4) {
      union { uint2 u; __half2 h[2]; } U;
      U.u = *(const uint2*)(Vb + (size_t)m * 64 + dsl);
      float2 f01 = __half22float2(U.h[0]);
      float2 f23 = __half22float2(U.h[1]);
      float am = att[hd][m];
      c0 = fmaf(am, f01.x, c0);
      c1 = fmaf(am, f01.y, c1);
      c2 = fmaf(am, f23.x, c2);
      c3 = fmaf(am, f23.y, c3);
    }
    c0 += __shfl_xor(c0, 16); c0 += __shfl_xor(c0, 32);
    c1 += __shfl_xor(c1, 16); c1 += __shfl_xor(c1, 32);
    c2 += __shfl_xor(c2, 16); c2 += __shfl_xor(c2, 32);
    c3 += __shfl_xor(c3, 16); c3 += __shfl_xor(c3, 32);
    if (g4 == 0) *(float4*)&ctxs[hd * 64 + dsl] = make_float4(c0, c1, c2, c3);
  }
  __syncthreads();

  // ---- GRU: thread t owns j = t; ctx and h both in LDS ----
  {
    int j = t;
    float air = b_ih[j], aiz = b_ih[512 + j], ain = b_ih[1024 + j];
    float ahr = b_hh[j], ahz = b_hh[512 + j], ahn = b_hh[1024 + j];
    const float* wi0 = W_ih + (size_t)j * 512;
    const float* wi1 = W_ih + (size_t)(512 + j) * 512;
    const float* wi2 = W_ih + (size_t)(1024 + j) * 512;
    const float* wh0 = W_hh + (size_t)j * 512;
    const float* wh1 = W_hh + (size_t)(512 + j) * 512;
    const float* wh2 = W_hh + (size_t)(1024 + j) * 512;
    #pragma unroll 2
    for (int k = 0; k < 512; k += 4) {
      float4 cc4 = *(const float4*)&ctxs[k];
      float4 hh4 = *(const float4*)&hs[k];
      float4 wa = *(const float4*)(wi0 + k);
      float4 wb = *(const float4*)(wi1 + k);
      float4 wc = *(const float4*)(wi2 + k);
      float4 wd = *(const float4*)(wh0 + k);
      float4 we = *(const float4*)(wh1 + k);
      float4 wf = *(const float4*)(wh2 + k);
      air = fmaf(cc4.x, wa.x, air); air = fmaf(cc4.y, wa.y, air); air = fmaf(cc4.z, wa.z, air); air = fmaf(cc4.w, wa.w, air);
      aiz = fmaf(cc4.x, wb.x, aiz); aiz = fmaf(cc4.y, wb.y, aiz); aiz = fmaf(cc4.z, wb.z, aiz); aiz = fmaf(cc4.w, wb.w, aiz);
      ain = fmaf(cc4.x, wc.x, ain); ain = fmaf(cc4.y, wc.y, ain); ain = fmaf(cc4.z, wc.z, ain); ain = fmaf(cc4.w, wc.w, ain);
      ahr = fmaf(hh4.x, wd.x, ahr); ahr = fmaf(hh4.y, wd.y, ahr); ahr = fmaf(hh4.z, wd.z, ahr); ahr = fmaf(hh4.w, wd.w, ahr);
      ahz = fmaf(hh4.x, we.x, ahz); ahz = fmaf(hh4.y, we.y, ahz); ahz = fmaf(hh4.z, we.z, ahz); ahz = fmaf(hh4.w, we.w, ahz);
      ahn = fmaf(hh4.x, wf.x, ahn); ahn = fmaf(hh4.y, wf.y, ahn); ahn = fmaf(hh4.z, wf.z, ahn); ahn = fmaf(hh4.w, wf.w, ahn);
    }
    float r = 1.f / (1.f + expf(-(air + ahr)));
    float z = 1.f / (1.f + expf(-(aiz + ahz)));
    float n = tanhf(fmaf(r, ahn, ain));
    float hp = hs[j];
    float hv = (1.f - z) * n + z * hp;
    h_new[(size_t)b * 512 + j] = hv;
    out_h[(size_t)step * 65536 + (size_t)b * 512 + j] = (step < lens[b]) ? hv : 0.f;
  }
}

// ---------------------------------------------------------------------------
extern "C" void kernel_launch(void* const* d_in, const int* in_sizes, int n_in,
                              void* d_out, int out_size, void* d_ws, size_t ws_size,
                              hipStream_t stream) {
  const float* memory = (const float*)d_in[0];
  const float* emb    = (const float*)d_in[1];
  const float* Wq     = (const float*)d_in[2];
  const float* bq     = (const float*)d_in[3];
  const float* Wk     = (const float*)d_in[4];
  const float* bk     = (const float*)d_in[5];
  const float* Wv     = (const float*)d_in[6];
  const float* bv     = (const float*)d_in[7];
  const float* W_ih   = (const float*)d_in[8];
  const float* W_hh   = (const float*)d_in[9];
  const float* b_ih   = (const float*)d_in[10];
  const float* b_hh   = (const float*)d_in[11];
  const float* Wfc    = (const float*)d_in[12];
  const float* bfc    = (const float*)d_in[13];
  const int* lens     = (const int*)d_in[14];

  __half* kpT = (__half*)d_ws;               // 33,554,432 halfs  [b][h][d][m]
  __half* vp  = kpT + 33554432;              // 33,554,432 halfs  [b][h][m][d]
  float* h0   = (float*)(vp + 33554432);     // 65,536 f
  float* h1   = h0 + 65536;                  // 65,536 f
  float* E2   = h1 + 65536;                  // 512,000 f (1000 x 512, includes bq)

  float* out   = (float*)d_out;
  float* out_o = out;                  // 160*128*1000
  float* out_h = out + 20480000;       // 160*128*512
  float* out_s = out_h + 10485760;     // 160*128*512

  kv_projT<<<8192, 256, 0, stream>>>(memory, Wk, bk, kpT);
  kv_proj<<<8192, 256, 0, stream>>>(memory, Wv, bv, vp);
  e2_kernel<<<128, 256, 0, stream>>>(emb, Wq, bq, E2);
  init_kernel<<<64, 256, 0, stream>>>(h0);

  for (int t = 0; t <= 160; ++t) {
    // h(t) lives in ((t&1) ? h0 : h1); h(-1)/h(0-prev) = h0 (zeroed)
    const float* hp = (t == 0) ? h0 : (((t - 1) & 1) ? h0 : h1);
    float* hn = (t & 1) ? h0 : h1;  // unused at t==160
    step_kernel<<<128, 512, 0, stream>>>(kpT, vp, E2, Wfc, bfc, Wq, W_ih, W_hh,
                                         b_ih, b_hh, hp, hn, lens, out_o, out_h,
                                         out_s, t);
  }
}